// Round 1
// baseline (332.547 us; speedup 1.0000x reference)
//
#include <hip/hip_runtime.h>
#include <stdint.h>

// Problem constants (fixed by reference)
#define BATCH 16
#define CH    512
#define HW    2304           // 48*48
#define BM    128
#define BN    128
#define BK    16
#define NT    (HW / BK)      // 144 K-tiles

// float -> order-preserving uint32 (monotone: a<b  <=>  key(a)<key(b))
__device__ __forceinline__ uint32_t f32_sortable(float f) {
    uint32_t u = __float_as_uint(f);
    return (u & 0x80000000u) ? ~u : (u | 0x80000000u);
}

// K1: energy = Q.K^T per batch (NT GEMM, fp32 vector FMA), fused row-argmax
// epilogue via packed atomicMax. best[b*CH+c] = (sortable(val)<<32) | ~d
__global__ __launch_bounds__(256, 2)
void energy_argmax_kernel(const float* __restrict__ q,    // rgb   [B][C][HW]
                          const float* __restrict__ kmat, // depth [B][C][HW]
                          unsigned long long* __restrict__ best) // [B][C]
{
    const int b  = blockIdx.z;
    const int c0 = blockIdx.y * BM;
    const int d0 = blockIdx.x * BN;
    const int tid = threadIdx.x;

    __shared__ float As[BK][BM + 4];
    __shared__ float Bs[BK][BN + 4];

    const float* qb = q    + (size_t)b * CH * HW;
    const float* kb = kmat + (size_t)b * CH * HW;

    // load mapping: L = tid + i*256 ; row = L>>2 ; k-offset = (L&3)*4
    float4 ra[2], rb[2];
    {
        #pragma unroll
        for (int i = 0; i < 2; ++i) {
            int L = tid + i * 256;
            int row = L >> 2, cv = (L & 3) * 4;
            ra[i] = *(const float4*)(qb + (size_t)(c0 + row) * HW + cv);
            rb[i] = *(const float4*)(kb + (size_t)(d0 + row) * HW + cv);
        }
    }

    float acc[8][8];
    #pragma unroll
    for (int i = 0; i < 8; ++i)
        #pragma unroll
        for (int j = 0; j < 8; ++j) acc[i][j] = 0.0f;

    const int tx = tid & 15;   // n dim (16)
    const int ty = tid >> 4;   // m dim (16)
    const int m0 = ty * 4, n0 = tx * 4;

    for (int kt = 0; kt < NT; ++kt) {
        __syncthreads();   // previous compute done -> LDS reusable
        #pragma unroll
        for (int i = 0; i < 2; ++i) {
            int L = tid + i * 256;
            int row = L >> 2, cv = (L & 3) * 4;
            As[cv + 0][row] = ra[i].x; As[cv + 1][row] = ra[i].y;
            As[cv + 2][row] = ra[i].z; As[cv + 3][row] = ra[i].w;
            Bs[cv + 0][row] = rb[i].x; Bs[cv + 1][row] = rb[i].y;
            Bs[cv + 2][row] = rb[i].z; Bs[cv + 3][row] = rb[i].w;
        }
        __syncthreads();
        if (kt + 1 < NT) {   // prefetch next tile into regs; latency hides under FMAs
            int k0 = (kt + 1) * BK;
            #pragma unroll
            for (int i = 0; i < 2; ++i) {
                int L = tid + i * 256;
                int row = L >> 2, cv = (L & 3) * 4;
                ra[i] = *(const float4*)(qb + (size_t)(c0 + row) * HW + k0 + cv);
                rb[i] = *(const float4*)(kb + (size_t)(d0 + row) * HW + k0 + cv);
            }
        }
        #pragma unroll
        for (int kk = 0; kk < BK; ++kk) {
            float a[8], bb[8];
            *(float4*)&a[0]  = *(const float4*)&As[kk][m0];
            *(float4*)&a[4]  = *(const float4*)&As[kk][m0 + 64];
            *(float4*)&bb[0] = *(const float4*)&Bs[kk][n0];
            *(float4*)&bb[4] = *(const float4*)&Bs[kk][n0 + 64];
            #pragma unroll
            for (int i = 0; i < 8; ++i)
                #pragma unroll
                for (int j = 0; j < 8; ++j)
                    acc[i][j] = fmaf(a[i], bb[j], acc[i][j]);
        }
    }

    // Epilogue: per-row argmax over this 128-col tile, then one atomic per row
    #pragma unroll
    for (int i = 0; i < 8; ++i) {
        int row = (i < 4) ? (m0 + i) : (64 + m0 + (i - 4));
        float vmax = acc[i][0];
        int   dmax = d0 + n0;
        #pragma unroll
        for (int j = 1; j < 8; ++j) {
            int col = (j < 4) ? (n0 + j) : (64 + n0 + (j - 4));
            float v = acc[i][j];
            if (v > vmax) { vmax = v; dmax = d0 + col; }
        }
        unsigned long long p =
            ((unsigned long long)f32_sortable(vmax) << 32) |
            (uint32_t)(~(uint32_t)dmax);   // ties -> smallest d (numpy argmax)
        // reduce across the 16 tx lanes of this ty group (butterfly)
        #pragma unroll
        for (int off = 1; off < 16; off <<= 1) {
            unsigned long long o = __shfl_xor(p, off, 64);
            if (o > p) p = o;
        }
        if (tx == 0)
            atomicMax(&best[(size_t)b * CH + c0 + row], p);
    }
}

// K2: out[b][c][:] = rgb[b][c][:] + depth[b][argmax][:]
__global__ __launch_bounds__(256)
void gather_add_kernel(const float* __restrict__ rgb,
                       const float* __restrict__ depth,
                       const unsigned long long* __restrict__ best,
                       float* __restrict__ out)
{
    const int row = blockIdx.x;          // b*CH + c
    const int b   = row >> 9;            // /512
    const uint32_t idx = ~(uint32_t)(best[row] & 0xFFFFFFFFull);
    const float4* src = (const float4*)(rgb   + (size_t)row * HW);
    const float4* dep = (const float4*)(depth + ((size_t)b * CH + idx) * HW);
    float4*       dst = (float4*)(out + (size_t)row * HW);
    for (int j = threadIdx.x; j < HW / 4; j += 256) {
        float4 a = src[j], d = dep[j];
        float4 r; r.x = a.x + d.x; r.y = a.y + d.y; r.z = a.z + d.z; r.w = a.w + d.w;
        dst[j] = r;
    }
}

extern "C" void kernel_launch(void* const* d_in, const int* in_sizes, int n_in,
                              void* d_out, int out_size, void* d_ws, size_t ws_size,
                              hipStream_t stream)
{
    const float* rgb   = (const float*)d_in[0];
    const float* depth = (const float*)d_in[1];
    float* out = (float*)d_out;
    unsigned long long* best = (unsigned long long*)d_ws;  // 16*512*8 = 64 KB

    hipMemsetAsync(best, 0, (size_t)BATCH * CH * sizeof(unsigned long long), stream);

    dim3 g1(CH / BN, CH / BM, BATCH);   // 4 x 4 x 16 = 256 blocks
    energy_argmax_kernel<<<g1, 256, 0, stream>>>(rgb, depth, best);

    gather_add_kernel<<<BATCH * CH, 256, 0, stream>>>(rgb, depth, best, out);
}